// Round 17
// baseline (1340.799 us; speedup 1.0000x reference)
//
#include <hip/hip_runtime.h>
#include <hip/hip_bf16.h>
#include <hip/hip_cooperative_groups.h>

namespace cgx = cooperative_groups;

// 3-layer SplineConv (3x3, degree 2, open spline).
// Round 17: cooperative mega-kernel, CAPACITY-SAFE. Round 16's coop launch of
//   G=1563 silently failed (absmax matched the unwritten-output stub): grid
//   exceeded co-residency and the error code was ignored. Now:
//   - G = min(TB, occupancy-query blocks/CU * 256 CUs)  (grid-stride loops
//     make any G correct)
//   - launch return code checked; on failure fall back to the proven
//     round-15 multi-kernel pipeline (231 us). Both paths deterministic.
// Phases (coop): P0 init | P1 count+rank | P2-P4 2N scan | P5 scatter |
//   P6 L1 | P7 L2 | P8 L3 | P9 final gather.  Per-layer structure = round 15:
//   TN=32 tiles, 18.9 KB LDS, per-tile MFMA acc write-through, erec prefetch.

typedef __attribute__((ext_vector_type(8))) short short8;
typedef __attribute__((ext_vector_type(4))) float f32x4;

__device__ __forceinline__ float blo(unsigned u) {
    union { unsigned u; float f; } x; x.u = u << 16; return x.f;
}
__device__ __forceinline__ float bhi(unsigned u) {
    union { unsigned u; float f; } x; x.u = u & 0xffff0000u; return x.f;
}
__device__ __forceinline__ unsigned short f2bf(float f) {
    union { float f; unsigned u; } x; x.f = f;
    unsigned r = x.u + 0x7fffu + ((x.u >> 16) & 1u);   // RNE
    return (unsigned short)(r >> 16);
}
__device__ __forceinline__ short8 cvt8(const float* p) {
    float4 a = *(const float4*)p;
    float4 b = *(const float4*)(p + 4);
    short8 r;
    r[0] = (short)f2bf(a.x); r[1] = (short)f2bf(a.y);
    r[2] = (short)f2bf(a.z); r[3] = (short)f2bf(a.w);
    r[4] = (short)f2bf(b.x); r[5] = (short)f2bf(b.y);
    r[6] = (short)f2bf(b.z); r[7] = (short)f2bf(b.w);
    return r;
}

#define YROW 296   // sY row stride in shorts (592 B, 16B-aligned)

// ---- M phase: msgs for tile n0's src-CSR segment, y from LDS; erec prefetch ----
__device__ __forceinline__ void m_phase(const unsigned short* sY,
                                        const int* __restrict__ sstart,
                                        const float4* __restrict__ erec,
                                        uint4* msgOut,
                                        int n0, int t, int N, int E)
{
    const int e0 = sstart[n0];
    const int e1 = (n0 + 32 < N) ? sstart[n0 + 32] : E;
    const int l  = t & 3;

    int e = e0 + (t >> 2);
    if (e >= e1) return;
    float4 r = erec[e];
    while (true) {
        const int en = e + 64;
        float4 rn;
        if (en < e1) rn = erec[en];

        const int srcl = __float_as_int(r.x) - n0;
        const int dp   = __float_as_int(r.y);
        const float p0 = r.z, p1 = r.w;

        const float qb[3] = {0.5f * (1.f - p0) * (1.f - p0), -p0 * p0 + p0 + 0.5f, 0.5f * p0 * p0};
        const float qa[3] = {0.5f * (1.f - p1) * (1.f - p1), -p1 * p1 + p1 + 0.5f, 0.5f * p1 * p1};

        const uint4* yb = (const uint4*)(sY + srcl * YROW) + l;
        float s[8] = {0.f, 0.f, 0.f, 0.f, 0.f, 0.f, 0.f, 0.f};
        #pragma unroll
        for (int a = 0; a < 3; ++a) {
            float z[8] = {0.f, 0.f, 0.f, 0.f, 0.f, 0.f, 0.f, 0.f};
            #pragma unroll
            for (int b = 0; b < 3; ++b) {
                uint4 v = yb[(a * 3 + b) * 4];
                const float cw = qb[b];
                z[0] = fmaf(cw, blo(v.x), z[0]); z[1] = fmaf(cw, bhi(v.x), z[1]);
                z[2] = fmaf(cw, blo(v.y), z[2]); z[3] = fmaf(cw, bhi(v.y), z[3]);
                z[4] = fmaf(cw, blo(v.z), z[4]); z[5] = fmaf(cw, bhi(v.z), z[5]);
                z[6] = fmaf(cw, blo(v.w), z[6]); z[7] = fmaf(cw, bhi(v.w), z[7]);
            }
            #pragma unroll
            for (int j = 0; j < 8; ++j) s[j] = fmaf(qa[a], z[j], s[j]);
        }

        union { uint4 u; __hip_bfloat162 h[4]; } o;
        #pragma unroll
        for (int j = 0; j < 4; ++j)
            o.h[j] = __float22bfloat162_rn(float2{s[2 * j], s[2 * j + 1]});
        msgOut[(size_t)dp * 4 + l] = o.u;

        if (en >= e1) break;
        r = rn; e = en;
    }
}

// ---- T core (TN=32): per-tile acc, written immediately (~8 live VGPRs) ----
template<int NHALF>  // 2: K=64, 1: K=32
__device__ __forceinline__ void t_core(short8 a0, short8 a1,
                                       const unsigned short* __restrict__ Wt,
                                       const float* __restrict__ bias,
                                       unsigned short* sY, float* aggOut,
                                       int n0, int rh, int cgp, int lc, int q, int N)
{
    const int CIN = NHALF * 32;
    #pragma unroll
    for (int j = 0; j < 10; ++j) {
        const int ti = cgp * 10 + j;
        const unsigned short* wp = Wt + ((size_t)(ti * 16 + lc)) * CIN + q * 8;
        f32x4 acc = (f32x4){0.f, 0.f, 0.f, 0.f};
        acc = __builtin_amdgcn_mfma_f32_16x16x32_bf16(a0, *(const short8*)wp, acc, 0, 0, 0);
        if (NHALF == 2)
            acc = __builtin_amdgcn_mfma_f32_16x16x32_bf16(a1, *(const short8*)(wp + 32), acc, 0, 0, 0);

        if (ti < 18) {
            #pragma unroll
            for (int r = 0; r < 4; ++r) {
                int nl = rh * 16 + q * 4 + r;
                sY[nl * YROW + ti * 16 + lc] = f2bf(acc[r]);
            }
        } else {
            int c = (ti - 18) * 16 + lc;
            float bv = bias[c];
            #pragma unroll
            for (int r = 0; r < 4; ++r) {
                int n = n0 + rh * 16 + q * 4 + r;
                if (n < N) aggOut[(size_t)n * 32 + c] = acc[r] + bv;
            }
        }
    }
}

// ---- G phase: lane builds its 8 A-frag channels (q*8..q*8+7) of node na ----
__device__ __forceinline__ short8 g_phase(const float* aggPrev, const uint4* msgIn,
                                          const int* __restrict__ dstart,
                                          int na, int q, int N, int E)
{
    const float* ap = aggPrev + (size_t)na * 32 + q * 8;
    float4 r0 = *(const float4*)ap;
    float4 r1 = *(const float4*)(ap + 4);
    float h[8] = {r0.x, r0.y, r0.z, r0.w, r1.x, r1.y, r1.z, r1.w};
    float g[8] = {0.f, 0.f, 0.f, 0.f, 0.f, 0.f, 0.f, 0.f};
    const int ge0 = dstart[na] - E;
    const int ge1 = ((na + 1 < N) ? dstart[na + 1] : 2 * E) - E;
    int e = ge0;
    for (; e + 2 <= ge1; e += 2) {
        uint4 v0 = msgIn[(size_t)e * 4 + q];
        uint4 v1 = msgIn[(size_t)(e + 1) * 4 + q];
        h[0] += blo(v0.x); h[1] += bhi(v0.x); h[2] += blo(v0.y); h[3] += bhi(v0.y);
        h[4] += blo(v0.z); h[5] += bhi(v0.z); h[6] += blo(v0.w); h[7] += bhi(v0.w);
        g[0] += blo(v1.x); g[1] += bhi(v1.x); g[2] += blo(v1.y); g[3] += bhi(v1.y);
        g[4] += blo(v1.z); g[5] += bhi(v1.z); g[6] += blo(v1.w); g[7] += bhi(v1.w);
    }
    if (e < ge1) {
        uint4 v = msgIn[(size_t)e * 4 + q];
        h[0] += blo(v.x); h[1] += bhi(v.x); h[2] += blo(v.y); h[3] += bhi(v.y);
        h[4] += blo(v.z); h[5] += bhi(v.z); h[6] += blo(v.w); h[7] += bhi(v.w);
    }
    union { short8 v; __hip_bfloat162 h2[4]; } pk;
    #pragma unroll
    for (int j = 0; j < 4; ++j)
        pk.h2[j] = __float22bfloat162_rn(float2{fmaxf(h[2 * j] + g[2 * j], 0.f),
                                                fmaxf(h[2 * j + 1] + g[2 * j + 1], 0.f)});
    return pk.v;
}

// ---- final-gather body (shared by coop P9 and fallback kernel) ----
__device__ __forceinline__ void gather_node(const int* __restrict__ dstart,
                                            const uint4* msg4, float* agg,
                                            int n, int l, int N, int E)
{
    const int e0 = dstart[n] - E;
    const int e1 = ((n + 1 < N) ? dstart[n + 1] : 2 * E) - E;
    float4* ap = (float4*)(agg + (size_t)n * 32 + l * 8);
    float4 A = ap[0], B = ap[1];
    float4 C = {0.f, 0.f, 0.f, 0.f}, D = {0.f, 0.f, 0.f, 0.f};
    const uint4* mp = msg4 + l;
    int e = e0;
    for (; e + 2 <= e1; e += 2) {
        uint4 v0 = mp[(size_t)e * 4];
        uint4 v1 = mp[(size_t)(e + 1) * 4];
        A.x += blo(v0.x); A.y += bhi(v0.x); A.z += blo(v0.y); A.w += bhi(v0.y);
        B.x += blo(v0.z); B.y += bhi(v0.z); B.z += blo(v0.w); B.w += bhi(v0.w);
        C.x += blo(v1.x); C.y += bhi(v1.x); C.z += blo(v1.y); C.w += bhi(v1.y);
        D.x += blo(v1.z); D.y += bhi(v1.z); D.z += blo(v1.w); D.w += bhi(v1.w);
    }
    if (e < e1) {
        uint4 v = mp[(size_t)e * 4];
        A.x += blo(v.x); A.y += bhi(v.x); A.z += blo(v.y); A.w += bhi(v.y);
        B.x += blo(v.z); B.y += bhi(v.z); B.z += blo(v.w); B.w += bhi(v.w);
    }
    A.x += C.x; A.y += C.y; A.z += C.z; A.w += C.w;
    B.x += D.x; B.y += D.y; B.z += D.z; B.w += D.w;
    A.x = fmaxf(A.x, 0.f); A.y = fmaxf(A.y, 0.f); A.z = fmaxf(A.z, 0.f); A.w = fmaxf(A.w, 0.f);
    B.x = fmaxf(B.x, 0.f); B.y = fmaxf(B.y, 0.f); B.z = fmaxf(B.z, 0.f); B.w = fmaxf(B.w, 0.f);
    ap[0] = A; ap[1] = B;
}

// ================= cooperative mega-kernel =================

__global__ __launch_bounds__(256, 8)
void mega(const float* x, const int* ei, const float* pseudo, const float* skip,
          const float* W1, const float* root1, const float* b1,
          const float* W2, const float* root2, const float* b2,
          unsigned short* msgA, unsigned short* msgB,
          float* agg1, float* agg2, float4* erec,
          int* start, int* bsum,
          unsigned short* Wt1, unsigned short* Wt2,
          float* out, int N, int E)
{
    cgx::grid_group grid = cgx::this_grid();
    __shared__ __align__(16) unsigned short sY[32 * YROW];   // 18,944 B
    const int t    = threadIdx.x;
    const int bid  = blockIdx.x;
    const int G    = gridDim.x;
    const int lane = t & 63;
    const int wv   = t >> 6;
    const int lc   = lane & 15, q = lane >> 4;
    const int rh   = wv & 1, cgp = wv >> 1;
    const int n2   = 2 * N;
    const int TB   = (N + 31) >> 5;
    uint2* rank = (uint2*)msgB;    // prep-only; msgB first written in P7
    int* si = (int*)sY;

    // P0: zero 2N histogram + build bf16 weight panels
    {
        const int itot = n2 + 320 * 96;
        for (int i = bid * 256 + t; i < itot; i += G * 256) {
            if (i < n2) { start[i] = 0; continue; }
            int j = i - n2;
            if (j < 320 * 64) {
                int col = j / 64, k = j % 64;
                float v = (col < 288) ? W1[((size_t)(col >> 5) * 64 + k) * 32 + (col & 31)]
                                      : root1[(size_t)k * 32 + (col - 288)];
                Wt1[j] = f2bf(v);
            } else {
                int jj = j - 320 * 64;
                int col = jj / 32, k = jj % 32;
                float v = (col < 288) ? W2[((size_t)(col >> 5) * 32 + k) * 32 + (col & 31)]
                                      : root2[(size_t)k * 32 + (col - 288)];
                Wt2[jj] = f2bf(v);
            }
        }
    }
    grid.sync();

    // P1: count both bins + capture ranks
    for (int e = bid * 256 + t; e < E; e += G * 256) {
        unsigned rs = atomicAdd((unsigned*)&start[ei[e]], 1u);
        unsigned rd = atomicAdd((unsigned*)&start[N + ei[E + e]], 1u);
        rank[e] = uint2{rs, rd};
    }
    grid.sync();

    // P2: 256-chunked local exclusive scan; chunk totals -> bsum
    const int nch = (n2 + 255) >> 8;
    for (int c = bid; c < nch; c += G) {
        int i = c * 256 + t;
        int v = (i < n2) ? start[i] : 0;
        si[t] = v;
        __syncthreads();
        for (int off = 1; off < 256; off <<= 1) {
            int add = (t >= off) ? si[t - off] : 0;
            __syncthreads();
            si[t] += add;
            __syncthreads();
        }
        if (i < n2) start[i] = si[t] - v;
        if (t == 255) bsum[c] = si[255];
        __syncthreads();
    }
    grid.sync();

    // P3: block 0 exclusive-scans bsum[nch] (nch <= 512)
    if (bid == 0) {
        int carry = 0;
        for (int base = 0; base < nch; base += 256) {
            int i = base + t;
            int v = (i < nch) ? bsum[i] : 0;
            si[t] = v;
            __syncthreads();
            for (int off = 1; off < 256; off <<= 1) {
                int add = (t >= off) ? si[t - off] : 0;
                __syncthreads();
                si[t] += add;
                __syncthreads();
            }
            if (i < nch) bsum[i] = si[t] - v + carry;
            carry += si[255];
            __syncthreads();
        }
    }
    grid.sync();

    // P4: add chunk prefixes
    for (int i = bid * 256 + t; i < n2; i += G * 256)
        start[i] += bsum[i >> 8];
    grid.sync();

    // P5: atomic-free scatter of packed edge records
    for (int e = bid * 256 + t; e < E; e += G * 256) {
        int sv = ei[e];
        int dv = ei[E + e];
        uint2 rk = rank[e];
        int ps = start[sv] + (int)rk.x;
        int pd = start[N + dv] + (int)rk.y - E;
        float4 r;
        r.x = __int_as_float(sv);
        r.y = __int_as_float(pd);
        r.z = pseudo[2 * (size_t)e];
        r.w = pseudo[2 * (size_t)e + 1];
        erec[ps] = r;
    }
    grid.sync();

    const int* dstart = start + N;

    // P6: Layer 1 (X = x) -> agg1, msgA
    for (int c = bid; c < TB; c += G) {
        const int n0 = c * 32;
        int na = n0 + rh * 16 + lc;
        if (na >= N) na = N - 1;
        const float* p = x + (size_t)na * 64 + q * 8;
        short8 a0 = cvt8(p);
        short8 a1 = cvt8(p + 32);
        t_core<2>(a0, a1, Wt1, b1, sY, agg1, n0, rh, cgp, lc, q, N);
        __syncthreads();
        m_phase(sY, start, erec, (uint4*)msgA, n0, t, N, E);
        __syncthreads();
    }
    grid.sync();

    // P7: Layer 2 (X = [relu(agg1+gather msgA) | skip]) -> agg2, msgB
    for (int c = bid; c < TB; c += G) {
        const int n0 = c * 32;
        int na = n0 + rh * 16 + lc;
        if (na >= N) na = N - 1;
        short8 a0 = g_phase(agg1, (const uint4*)msgA, dstart, na, q, N, E);
        short8 a1 = cvt8(skip + (size_t)na * 32 + q * 8);
        t_core<2>(a0, a1, Wt1, b1, sY, agg2, n0, rh, cgp, lc, q, N);
        __syncthreads();
        m_phase(sY, start, erec, (uint4*)msgB, n0, t, N, E);
        __syncthreads();
    }
    grid.sync();

    // P8: Layer 3 (X = relu(agg2+gather msgB)) -> out(root), msgA
    for (int c = bid; c < TB; c += G) {
        const int n0 = c * 32;
        int na = n0 + rh * 16 + lc;
        if (na >= N) na = N - 1;
        short8 a0 = g_phase(agg2, (const uint4*)msgB, dstart, na, q, N, E);
        short8 a1;
        t_core<1>(a0, a1, Wt2, b2, sY, out, n0, rh, cgp, lc, q, N);
        __syncthreads();
        m_phase(sY, start, erec, (uint4*)msgA, n0, t, N, E);
        __syncthreads();
    }
    grid.sync();

    // P9: final gather: out = relu(out + sum msgA rows)
    {
        const int GB = (N + 63) >> 6;
        const int l = t & 3;
        for (int c = bid; c < GB; c += G) {
            const int n = c * 64 + (t >> 2);
            if (n < N) gather_node(dstart, (const uint4*)msgA, out, n, l, N, E);
        }
    }
}

// ================= fallback multi-kernel path (round 15) =================

__global__ __launch_bounds__(256)
void init_kernel(int* __restrict__ hist, int n2,
                 const float* __restrict__ W1, const float* __restrict__ root1,
                 const float* __restrict__ W2, const float* __restrict__ root2,
                 unsigned short* __restrict__ Wt1, unsigned short* __restrict__ Wt2)
{
    int i = blockIdx.x * 256 + threadIdx.x;
    if (i < n2) { hist[i] = 0; return; }
    int j = i - n2;
    if (j < 320 * 64) {
        int col = j / 64, k = j % 64;
        float v = (col < 288) ? W1[((size_t)(col >> 5) * 64 + k) * 32 + (col & 31)]
                              : root1[(size_t)k * 32 + (col - 288)];
        Wt1[j] = f2bf(v);
    } else if (j < 320 * 96) {
        int jj = j - 320 * 64;
        int col = jj / 32, k = jj % 32;
        float v = (col < 288) ? W2[((size_t)(col >> 5) * 32 + k) * 32 + (col & 31)]
                              : root2[(size_t)k * 32 + (col - 288)];
        Wt2[jj] = f2bf(v);
    }
}

__global__ __launch_bounds__(256)
void count_rank_kernel(const int* __restrict__ ei, int* __restrict__ hist,
                       uint2* __restrict__ rank, int N, int E)
{
    int e = blockIdx.x * 256 + threadIdx.x;
    if (e >= E) return;
    unsigned rs = atomicAdd((unsigned*)&hist[ei[e]], 1u);
    unsigned rd = atomicAdd((unsigned*)&hist[N + ei[E + e]], 1u);
    rank[e] = uint2{rs, rd};
}

__global__ __launch_bounds__(1024)
void scan1_kernel(int* __restrict__ hist, int* __restrict__ bsum, int n)
{
    __shared__ int s[1024];
    int tid = threadIdx.x;
    int i = blockIdx.x * 1024 + tid;
    int v = (i < n) ? hist[i] : 0;
    s[tid] = v;
    __syncthreads();
    for (int off = 1; off < 1024; off <<= 1) {
        int add = (tid >= off) ? s[tid - off] : 0;
        __syncthreads();
        s[tid] += add;
        __syncthreads();
    }
    if (i < n) hist[i] = s[tid] - v;
    if (tid == 1023) bsum[blockIdx.x] = s[1023];
}

__global__ __launch_bounds__(1024)
void scan3_kernel(int* __restrict__ hist, const int* __restrict__ bsum, int n)
{
    __shared__ int sred[128];
    int tid = threadIdx.x;
    int b = blockIdx.x;
    if (tid < 128) sred[tid] = (tid < b) ? bsum[tid] : 0;
    __syncthreads();
    for (int off = 64; off > 0; off >>= 1) {
        if (tid < off) sred[tid] += sred[tid + off];
        __syncthreads();
    }
    int pre = sred[0];
    int i = b * 1024 + tid;
    if (i < n) hist[i] += pre;
}

__global__ __launch_bounds__(256)
void scatter_plain_kernel(const int* __restrict__ ei, const float* __restrict__ pseudo,
                          const int* __restrict__ start, const uint2* __restrict__ rank,
                          float4* __restrict__ erec, int N, int E)
{
    int e = blockIdx.x * 256 + threadIdx.x;
    if (e >= E) return;
    int sv = ei[e];
    int dv = ei[E + e];
    uint2 rk = rank[e];
    int ps = start[sv] + (int)rk.x;
    int pd = start[N + dv] + (int)rk.y - E;
    float4 r;
    r.x = __int_as_float(sv);
    r.y = __int_as_float(pd);
    r.z = pseudo[2 * (size_t)e];
    r.w = pseudo[2 * (size_t)e + 1];
    erec[ps] = r;
}

__global__ __launch_bounds__(256, 8)
void fb_layer_tm0(const float* __restrict__ Xa,
                  const unsigned short* __restrict__ Wt, const float* __restrict__ bias,
                  const int* __restrict__ sstart, const float4* __restrict__ erec,
                  float* __restrict__ aggOut, uint4* __restrict__ msgOut, int N, int E)
{
    __shared__ __align__(16) unsigned short sY[32 * YROW];
    const int t = threadIdx.x, wv = t >> 6, lane = t & 63;
    const int lc = lane & 15, q = lane >> 4;
    const int rh = wv & 1, cgp = wv >> 1;
    const int n0 = blockIdx.x * 32;
    int na = n0 + rh * 16 + lc;
    if (na >= N) na = N - 1;
    const float* p = Xa + (size_t)na * 64 + q * 8;
    short8 a0 = cvt8(p);
    short8 a1 = cvt8(p + 32);
    t_core<2>(a0, a1, Wt, bias, sY, aggOut, n0, rh, cgp, lc, q, N);
    __syncthreads();
    m_phase(sY, sstart, erec, msgOut, n0, t, N, E);
}

template<int MODE>
__global__ __launch_bounds__(256, 8)
void fb_layer_gtm(const float* __restrict__ aggPrev, const float* __restrict__ skipv,
                  const unsigned short* __restrict__ Wt, const float* __restrict__ bias,
                  const int* __restrict__ sstart, const int* __restrict__ dstart,
                  const float4* __restrict__ erec,
                  const uint4* __restrict__ msgIn, uint4* __restrict__ msgOut,
                  float* __restrict__ aggOut, int N, int E)
{
    __shared__ __align__(16) unsigned short sY[32 * YROW];
    const int t = threadIdx.x, wv = t >> 6, lane = t & 63;
    const int lc = lane & 15, q = lane >> 4;
    const int rh = wv & 1, cgp = wv >> 1;
    const int n0 = blockIdx.x * 32;
    int na = n0 + rh * 16 + lc;
    if (na >= N) na = N - 1;
    short8 a0 = g_phase(aggPrev, msgIn, dstart, na, q, N, E);
    short8 a1;
    if (MODE == 1) a1 = cvt8(skipv + (size_t)na * 32 + q * 8);
    t_core<(MODE == 1) ? 2 : 1>(a0, a1, Wt, bias, sY, aggOut, n0, rh, cgp, lc, q, N);
    __syncthreads();
    m_phase(sY, sstart, erec, msgOut, n0, t, N, E);
}

__global__ __launch_bounds__(256)
void fb_gather(const int* __restrict__ dstart, const uint4* __restrict__ msg4,
               float* __restrict__ agg, int N, int E)
{
    const int t = threadIdx.x;
    const int n = blockIdx.x * 64 + (t >> 2);
    if (n >= N) return;
    gather_node(dstart, msg4, agg, n, t & 3, N, E);
}

extern "C" void kernel_launch(void* const* d_in, const int* in_sizes, int n_in,
                              void* d_out, int out_size, void* d_ws, size_t ws_size,
                              hipStream_t stream) {
    const float* x      = (const float*)d_in[0];
    const int*   ei     = (const int*)  d_in[1];
    const float* pseudo = (const float*)d_in[2];
    const float* skip   = (const float*)d_in[3];
    const float* W1     = (const float*)d_in[4];
    const float* root1  = (const float*)d_in[5];
    const float* b1     = (const float*)d_in[6];
    const float* W2     = (const float*)d_in[7];
    const float* root2  = (const float*)d_in[8];
    const float* b2     = (const float*)d_in[9];

    int N = in_sizes[0] / 64;
    int E = in_sizes[1] / 2;
    float* out = (float*)d_out;

    // ws (~71 MB): msgA[E*32 bf16] msgB[E*32 bf16] agg1[N*32] agg2[N*32]
    //              erec[E f4] start[2N] bsum[512] Wt1 Wt2; rank aliases msgB
    unsigned short* msgA = (unsigned short*)d_ws;
    unsigned short* msgB = msgA + (size_t)E * 32;
    float*  agg1  = (float*)(msgB + (size_t)E * 32);
    float*  agg2  = agg1 + (size_t)N * 32;
    float4* erec  = (float4*)(agg2 + (size_t)N * 32);
    int*    start = (int*)(erec + E);
    int*    bsum  = start + 2 * N;
    unsigned short* Wt1 = (unsigned short*)(bsum + 512);
    unsigned short* Wt2 = Wt1 + 320 * 64;
    uint2*  rank  = (uint2*)msgB;
    int* dstart = start + N;

    const int TB = (N + 31) / 32;

    // ---- capacity-safe cooperative attempt ----
    int maxBpc = 0;
    hipError_t qerr = hipOccupancyMaxActiveBlocksPerMultiprocessor(
        &maxBpc, reinterpret_cast<const void*>(mega), 256, 0);
    hipError_t lerr = hipErrorUnknown;
    if (qerr == hipSuccess && maxBpc > 0) {
        int G = maxBpc * 256;          // 256 CUs on MI355X
        if (G > TB) G = TB;
        void* args[] = {
            (void*)&x, (void*)&ei, (void*)&pseudo, (void*)&skip,
            (void*)&W1, (void*)&root1, (void*)&b1,
            (void*)&W2, (void*)&root2, (void*)&b2,
            (void*)&msgA, (void*)&msgB,
            (void*)&agg1, (void*)&agg2, (void*)&erec,
            (void*)&start, (void*)&bsum,
            (void*)&Wt1, (void*)&Wt2,
            (void*)&out, (void*)&N, (void*)&E
        };
        lerr = hipLaunchCooperativeKernel(reinterpret_cast<void*>(mega),
                                          dim3(G), dim3(256), args, 0, stream);
    }
    if (lerr == hipSuccess) return;

    // ---- fallback: proven round-15 multi-kernel pipeline ----
    const dim3 blk(256);
    const int gb   = (N + 63) / 64;
    const int e256 = (E + 255) / 256;
    const int n2k  = (2 * N + 1023) / 1024;
    const int itot = 2 * N + 320 * 96;

    init_kernel<<<(itot + 255) / 256, blk, 0, stream>>>(start, 2 * N, W1, root1, W2, root2, Wt1, Wt2);
    count_rank_kernel<<<e256, blk, 0, stream>>>(ei, start, rank, N, E);
    scan1_kernel<<<n2k, 1024, 0, stream>>>(start, bsum, 2 * N);
    scan3_kernel<<<n2k, 1024, 0, stream>>>(start, bsum, 2 * N);
    scatter_plain_kernel<<<e256, blk, 0, stream>>>(ei, pseudo, start, rank, erec, N, E);

    fb_layer_tm0<<<TB, blk, 0, stream>>>(x, Wt1, b1, start, erec, agg1, (uint4*)msgA, N, E);
    fb_layer_gtm<1><<<TB, blk, 0, stream>>>(agg1, skip, Wt1, b1, start, dstart, erec,
                                            (const uint4*)msgA, (uint4*)msgB, agg2, N, E);
    fb_layer_gtm<2><<<TB, blk, 0, stream>>>(agg2, nullptr, Wt2, b2, start, dstart, erec,
                                            (const uint4*)msgB, (uint4*)msgA, out, N, E);
    fb_gather<<<gb, blk, 0, stream>>>(dstart, (const uint4*)msgA, out, N, E);
}

// Round 18
// 228.649 us; speedup vs baseline: 5.8640x; 5.8640x over previous
//
#include <hip/hip_runtime.h>
#include <hip/hip_bf16.h>

// 3-layer SplineConv (3x3, degree 2, open spline). Atomic-free, deep fusion.
// Round 18: revert cooperative (grid.sync on 8 non-coherent XCDs costs a full
//   L2 flush per sync -- 5.8x slower, round 17). Back to round-15 pipeline
//   (231 us) + ONE change: layer_gtm's gather was executed 4x redundantly
//   (4 waves share each row-half's 16 nodes). Now a block-cooperative gather:
//   128 threads (4 lanes/node) sum msgIn+root, relu, into LDS sH[32][33]
//   (aliased over sY, consumed before sY is written); every lane then reads
//   its 8 A-frag channels from LDS. Gather work and its dependent chain /4.
// Pipeline: init | count+rank | scan1 | scan3 | scatter(atomic-free) |
//   L1 tm0 | L2 gtm | L3 gtm | final gather.  TN=32 tiles, 18.9 KB LDS,
//   per-tile MFMA acc write-through (VGPR<=64, 8 blocks/CU), erec prefetch.

typedef __attribute__((ext_vector_type(8))) short short8;
typedef __attribute__((ext_vector_type(4))) float f32x4;

__device__ __forceinline__ float blo(unsigned u) {
    union { unsigned u; float f; } x; x.u = u << 16; return x.f;
}
__device__ __forceinline__ float bhi(unsigned u) {
    union { unsigned u; float f; } x; x.u = u & 0xffff0000u; return x.f;
}
__device__ __forceinline__ unsigned short f2bf(float f) {
    union { float f; unsigned u; } x; x.f = f;
    unsigned r = x.u + 0x7fffu + ((x.u >> 16) & 1u);   // RNE
    return (unsigned short)(r >> 16);
}
__device__ __forceinline__ short8 cvt8(const float* p) {
    float4 a = *(const float4*)p;
    float4 b = *(const float4*)(p + 4);
    short8 r;
    r[0] = (short)f2bf(a.x); r[1] = (short)f2bf(a.y);
    r[2] = (short)f2bf(a.z); r[3] = (short)f2bf(a.w);
    r[4] = (short)f2bf(b.x); r[5] = (short)f2bf(b.y);
    r[6] = (short)f2bf(b.z); r[7] = (short)f2bf(b.w);
    return r;
}

#define YROW 296   // sY row stride in shorts (592 B, 16B-aligned)

// ---- M phase: msgs for tile n0's src-CSR segment, y from LDS; erec prefetch ----
__device__ __forceinline__ void m_phase(const unsigned short* sY,
                                        const int* __restrict__ sstart,
                                        const float4* __restrict__ erec,
                                        uint4* __restrict__ msgOut,
                                        int n0, int t, int N, int E)
{
    const int e0 = sstart[n0];
    const int e1 = (n0 + 32 < N) ? sstart[n0 + 32] : E;
    const int l  = t & 3;

    int e = e0 + (t >> 2);
    if (e >= e1) return;
    float4 r = erec[e];
    while (true) {
        const int en = e + 64;
        float4 rn;
        if (en < e1) rn = erec[en];     // prefetch hides global latency

        const int srcl = __float_as_int(r.x) - n0;
        const int dp   = __float_as_int(r.y);
        const float p0 = r.z, p1 = r.w;

        const float qb[3] = {0.5f * (1.f - p0) * (1.f - p0), -p0 * p0 + p0 + 0.5f, 0.5f * p0 * p0};
        const float qa[3] = {0.5f * (1.f - p1) * (1.f - p1), -p1 * p1 + p1 + 0.5f, 0.5f * p1 * p1};

        const uint4* yb = (const uint4*)(sY + srcl * YROW) + l;
        float s[8] = {0.f, 0.f, 0.f, 0.f, 0.f, 0.f, 0.f, 0.f};
        #pragma unroll
        for (int a = 0; a < 3; ++a) {
            float z[8] = {0.f, 0.f, 0.f, 0.f, 0.f, 0.f, 0.f, 0.f};
            #pragma unroll
            for (int b = 0; b < 3; ++b) {
                uint4 v = yb[(a * 3 + b) * 4];
                const float cw = qb[b];
                z[0] = fmaf(cw, blo(v.x), z[0]); z[1] = fmaf(cw, bhi(v.x), z[1]);
                z[2] = fmaf(cw, blo(v.y), z[2]); z[3] = fmaf(cw, bhi(v.y), z[3]);
                z[4] = fmaf(cw, blo(v.z), z[4]); z[5] = fmaf(cw, bhi(v.z), z[5]);
                z[6] = fmaf(cw, blo(v.w), z[6]); z[7] = fmaf(cw, bhi(v.w), z[7]);
            }
            #pragma unroll
            for (int j = 0; j < 8; ++j) s[j] = fmaf(qa[a], z[j], s[j]);
        }

        union { uint4 u; __hip_bfloat162 h[4]; } o;
        #pragma unroll
        for (int j = 0; j < 4; ++j)
            o.h[j] = __float22bfloat162_rn(float2{s[2 * j], s[2 * j + 1]});
        msgOut[(size_t)dp * 4 + l] = o.u;

        if (en >= e1) break;
        r = rn; e = en;
    }
}

// ---- T core (TN=32): per-tile acc, written immediately (~8 live VGPRs) ----
template<int NHALF>  // 2: K=64, 1: K=32
__device__ __forceinline__ void t_core(short8 a0, short8 a1,
                                       const unsigned short* __restrict__ Wt,
                                       const float* __restrict__ bias,
                                       unsigned short* sY, float* __restrict__ aggOut,
                                       int n0, int rh, int cgp, int lc, int q, int N)
{
    const int CIN = NHALF * 32;
    #pragma unroll
    for (int j = 0; j < 10; ++j) {
        const int ti = cgp * 10 + j;
        const unsigned short* wp = Wt + ((size_t)(ti * 16 + lc)) * CIN + q * 8;
        f32x4 acc = (f32x4){0.f, 0.f, 0.f, 0.f};
        acc = __builtin_amdgcn_mfma_f32_16x16x32_bf16(a0, *(const short8*)wp, acc, 0, 0, 0);
        if (NHALF == 2)
            acc = __builtin_amdgcn_mfma_f32_16x16x32_bf16(a1, *(const short8*)(wp + 32), acc, 0, 0, 0);

        if (ti < 18) {
            #pragma unroll
            for (int r = 0; r < 4; ++r) {
                int nl = rh * 16 + q * 4 + r;
                sY[nl * YROW + ti * 16 + lc] = f2bf(acc[r]);
            }
        } else {
            int c = (ti - 18) * 16 + lc;
            float bv = bias[c];
            #pragma unroll
            for (int r = 0; r < 4; ++r) {
                int n = n0 + rh * 16 + q * 4 + r;
                if (n < N) aggOut[(size_t)n * 32 + c] = acc[r] + bv;
            }
        }
    }
}

// L1: X = x [N,64] from global
__global__ __launch_bounds__(256, 8)
void layer_tm0(const float* __restrict__ Xa,
               const unsigned short* __restrict__ Wt, const float* __restrict__ bias,
               const int* __restrict__ sstart, const float4* __restrict__ erec,
               float* __restrict__ aggOut, uint4* __restrict__ msgOut, int N, int E)
{
    __shared__ __align__(16) unsigned short sY[32 * YROW];   // 18,944 B
    const int t = threadIdx.x, wv = t >> 6, lane = t & 63;
    const int lc = lane & 15, q = lane >> 4;
    const int rh = wv & 1, cgp = wv >> 1;
    const int n0 = blockIdx.x * 32;

    int na = n0 + rh * 16 + lc;
    if (na >= N) na = N - 1;
    const float* p = Xa + (size_t)na * 64 + q * 8;
    short8 a0 = cvt8(p);
    short8 a1 = cvt8(p + 32);

    t_core<2>(a0, a1, Wt, bias, sY, aggOut, n0, rh, cgp, lc, q, N);
    __syncthreads();
    m_phase(sY, sstart, erec, msgOut, n0, t, N, E);
}

// L2 (MODE 1): X = [relu(aggPrev + gather msgIn) | skip]; L3 (MODE 2): X = relu(...)
// Round 18: block-cooperative gather into sH (LDS, aliased over sY).
template<int MODE>
__global__ __launch_bounds__(256, 8)
void layer_gtm(const float* __restrict__ aggPrev, const float* __restrict__ skipv,
               const unsigned short* __restrict__ Wt, const float* __restrict__ bias,
               const int* __restrict__ sstart, const int* __restrict__ dstart,
               const float4* __restrict__ erec,
               const uint4* __restrict__ msgIn, uint4* __restrict__ msgOut,
               float* __restrict__ aggOut, int N, int E)
{
    __shared__ __align__(16) unsigned short sY[32 * YROW];
    float* sH = (float*)sY;    // [32][33] fp32 = 4224 B; consumed before sY written
    const int t = threadIdx.x, wv = t >> 6, lane = t & 63;
    const int lc = lane & 15, q = lane >> 4;
    const int rh = wv & 1, cgp = wv >> 1;
    const int n0 = blockIdx.x * 32;

    // ---- cooperative G phase: 128 threads, 4 lanes per node ----
    if (t < 128) {
        const int nl = t >> 2;
        const int l  = t & 3;
        int n = n0 + nl;
        if (n >= N) n = N - 1;               // duplicate-gather padding rows
        const float* ap = aggPrev + (size_t)n * 32 + l * 8;
        float4 A = *(const float4*)ap;
        float4 B = *(const float4*)(ap + 4);
        float4 C = {0.f, 0.f, 0.f, 0.f}, D = {0.f, 0.f, 0.f, 0.f};
        const int e0 = dstart[n] - E;
        const int e1 = ((n + 1 < N) ? dstart[n + 1] : 2 * E) - E;
        const uint4* mp = msgIn + l;
        int e = e0;
        for (; e + 2 <= e1; e += 2) {
            uint4 v0 = mp[(size_t)e * 4];
            uint4 v1 = mp[(size_t)(e + 1) * 4];
            A.x += blo(v0.x); A.y += bhi(v0.x); A.z += blo(v0.y); A.w += bhi(v0.y);
            B.x += blo(v0.z); B.y += bhi(v0.z); B.z += blo(v0.w); B.w += bhi(v0.w);
            C.x += blo(v1.x); C.y += bhi(v1.x); C.z += blo(v1.y); C.w += bhi(v1.y);
            D.x += blo(v1.z); D.y += bhi(v1.z); D.z += blo(v1.w); D.w += bhi(v1.w);
        }
        if (e < e1) {
            uint4 v = mp[(size_t)e * 4];
            A.x += blo(v.x); A.y += bhi(v.x); A.z += blo(v.y); A.w += bhi(v.y);
            B.x += blo(v.z); B.y += bhi(v.z); B.z += blo(v.w); B.w += bhi(v.w);
        }
        float* hp = sH + nl * 33 + l * 8;
        hp[0] = fmaxf(A.x + C.x, 0.f); hp[1] = fmaxf(A.y + C.y, 0.f);
        hp[2] = fmaxf(A.z + C.z, 0.f); hp[3] = fmaxf(A.w + C.w, 0.f);
        hp[4] = fmaxf(B.x + D.x, 0.f); hp[5] = fmaxf(B.y + D.y, 0.f);
        hp[6] = fmaxf(B.z + D.z, 0.f); hp[7] = fmaxf(B.w + D.w, 0.f);
    }
    __syncthreads();

    // every lane reads its 8 A-frag channels from sH (2-way conflicts max)
    const float* hp = sH + (rh * 16 + lc) * 33 + q * 8;
    union { short8 v; __hip_bfloat162 h2[4]; } pk;
    #pragma unroll
    for (int j = 0; j < 4; ++j)
        pk.h2[j] = __float22bfloat162_rn(float2{hp[2 * j], hp[2 * j + 1]});
    short8 a0 = pk.v;
    short8 a1;
    if (MODE == 1) {
        int na = n0 + rh * 16 + lc;
        if (na >= N) na = N - 1;
        a1 = cvt8(skipv + (size_t)na * 32 + q * 8);
    }
    __syncthreads();   // all sH reads done before t_core overwrites sY

    t_core<(MODE == 1) ? 2 : 1>(a0, a1, Wt, bias, sY, aggOut, n0, rh, cgp, lc, q, N);
    __syncthreads();
    m_phase(sY, sstart, erec, msgOut, n0, t, N, E);
}

// final gather: out = relu(out + sum msg rows); unroll x2, dual accumulators
__global__ __launch_bounds__(256)
void gather_kernel(const int* __restrict__ dstart, const uint4* __restrict__ msg4,
                   float* __restrict__ agg, int N, int E)
{
    const int t = threadIdx.x;
    const int n = blockIdx.x * 64 + (t >> 2);
    if (n >= N) return;
    const int l = t & 3;

    const int e0 = dstart[n] - E;
    const int e1 = ((n + 1 < N) ? dstart[n + 1] : 2 * E) - E;

    float4* ap = (float4*)(agg + (size_t)n * 32 + l * 8);
    float4 A = ap[0], B = ap[1];
    float4 C = {0.f, 0.f, 0.f, 0.f}, D = {0.f, 0.f, 0.f, 0.f};
    const uint4* mp = msg4 + l;
    int e = e0;
    for (; e + 2 <= e1; e += 2) {
        uint4 v0 = mp[(size_t)e * 4];
        uint4 v1 = mp[(size_t)(e + 1) * 4];
        A.x += blo(v0.x); A.y += bhi(v0.x); A.z += blo(v0.y); A.w += bhi(v0.y);
        B.x += blo(v0.z); B.y += bhi(v0.z); B.z += blo(v0.w); B.w += bhi(v0.w);
        C.x += blo(v1.x); C.y += bhi(v1.x); C.z += blo(v1.y); C.w += bhi(v1.y);
        D.x += blo(v1.z); D.y += bhi(v1.z); D.z += blo(v1.w); D.w += bhi(v1.w);
    }
    if (e < e1) {
        uint4 v = mp[(size_t)e * 4];
        A.x += blo(v.x); A.y += bhi(v.x); A.z += blo(v.y); A.w += bhi(v.y);
        B.x += blo(v.z); B.y += bhi(v.z); B.z += blo(v.w); B.w += bhi(v.w);
    }
    A.x += C.x; A.y += C.y; A.z += C.z; A.w += C.w;
    B.x += D.x; B.y += D.y; B.z += D.z; B.w += D.w;
    A.x = fmaxf(A.x, 0.f); A.y = fmaxf(A.y, 0.f); A.z = fmaxf(A.z, 0.f); A.w = fmaxf(A.w, 0.f);
    B.x = fmaxf(B.x, 0.f); B.y = fmaxf(B.y, 0.f); B.z = fmaxf(B.z, 0.f); B.w = fmaxf(B.w, 0.f);
    ap[0] = A; ap[1] = B;
}

// ---------- prep ----------

__global__ __launch_bounds__(256)
void init_kernel(int* __restrict__ hist, int n2,
                 const float* __restrict__ W1, const float* __restrict__ root1,
                 const float* __restrict__ W2, const float* __restrict__ root2,
                 unsigned short* __restrict__ Wt1, unsigned short* __restrict__ Wt2)
{
    int i = blockIdx.x * 256 + threadIdx.x;
    if (i < n2) { hist[i] = 0; return; }
    int j = i - n2;
    if (j < 320 * 64) {
        int col = j / 64, k = j % 64;
        float v = (col < 288) ? W1[((size_t)(col >> 5) * 64 + k) * 32 + (col & 31)]
                              : root1[(size_t)k * 32 + (col - 288)];
        Wt1[j] = f2bf(v);
    } else if (j < 320 * 96) {
        int jj = j - 320 * 64;
        int col = jj / 32, k = jj % 32;
        float v = (col < 288) ? W2[((size_t)(col >> 5) * 32 + k) * 32 + (col & 31)]
                              : root2[(size_t)k * 32 + (col - 288)];
        Wt2[jj] = f2bf(v);
    }
}

__global__ __launch_bounds__(256)
void count_rank_kernel(const int* __restrict__ ei, int* __restrict__ hist,
                       uint2* __restrict__ rank, int N, int E)
{
    int e = blockIdx.x * 256 + threadIdx.x;
    if (e >= E) return;
    unsigned rs = atomicAdd((unsigned*)&hist[ei[e]], 1u);
    unsigned rd = atomicAdd((unsigned*)&hist[N + ei[E + e]], 1u);
    rank[e] = uint2{rs, rd};
}

__global__ __launch_bounds__(1024)
void scan1_kernel(int* __restrict__ hist, int* __restrict__ bsum, int n)
{
    __shared__ int s[1024];
    int tid = threadIdx.x;
    int i = blockIdx.x * 1024 + tid;
    int v = (i < n) ? hist[i] : 0;
    s[tid] = v;
    __syncthreads();
    for (int off = 1; off < 1024; off <<= 1) {
        int add = (tid >= off) ? s[tid - off] : 0;
        __syncthreads();
        s[tid] += add;
        __syncthreads();
    }
    if (i < n) hist[i] = s[tid] - v;
    if (tid == 1023) bsum[blockIdx.x] = s[1023];
}

__global__ __launch_bounds__(1024)
void scan3_kernel(int* __restrict__ hist, const int* __restrict__ bsum, int n)
{
    __shared__ int sred[128];
    int tid = threadIdx.x;
    int b = blockIdx.x;
    if (tid < 128) sred[tid] = (tid < b) ? bsum[tid] : 0;
    __syncthreads();
    for (int off = 64; off > 0; off >>= 1) {
        if (tid < off) sred[tid] += sred[tid + off];
        __syncthreads();
    }
    int pre = sred[0];
    int i = b * 1024 + tid;
    if (i < n) hist[i] += pre;
}

__global__ __launch_bounds__(256)
void scatter_plain_kernel(const int* __restrict__ ei, const float* __restrict__ pseudo,
                          const int* __restrict__ start, const uint2* __restrict__ rank,
                          float4* __restrict__ erec, int N, int E)
{
    int e = blockIdx.x * 256 + threadIdx.x;
    if (e >= E) return;
    int sv = ei[e];
    int dv = ei[E + e];
    uint2 rk = rank[e];
    int ps = start[sv] + (int)rk.x;
    int pd = start[N + dv] + (int)rk.y - E;
    float4 r;
    r.x = __int_as_float(sv);
    r.y = __int_as_float(pd);
    r.z = pseudo[2 * (size_t)e];
    r.w = pseudo[2 * (size_t)e + 1];
    erec[ps] = r;
}

extern "C" void kernel_launch(void* const* d_in, const int* in_sizes, int n_in,
                              void* d_out, int out_size, void* d_ws, size_t ws_size,
                              hipStream_t stream) {
    const float* x      = (const float*)d_in[0];
    const int*   ei     = (const int*)  d_in[1];
    const float* pseudo = (const float*)d_in[2];
    const float* skip   = (const float*)d_in[3];
    const float* W1     = (const float*)d_in[4];
    const float* root1  = (const float*)d_in[5];
    const float* b1     = (const float*)d_in[6];
    const float* W2     = (const float*)d_in[7];
    const float* root2  = (const float*)d_in[8];
    const float* b2     = (const float*)d_in[9];

    const int N = in_sizes[0] / 64;
    const int E = in_sizes[1] / 2;
    float* out = (float*)d_out;

    // ws (~71 MB): msgA[E*32 bf16] msgB[E*32 bf16] agg1[N*32] agg2[N*32]
    //              erec[E f4] start[2N] bsum[256] Wt1 Wt2; rank aliases msgB
    unsigned short* msgA = (unsigned short*)d_ws;
    unsigned short* msgB = msgA + (size_t)E * 32;
    float*  agg1  = (float*)(msgB + (size_t)E * 32);
    float*  agg2  = agg1 + (size_t)N * 32;
    float4* erec  = (float4*)(agg2 + (size_t)N * 32);
    int*    start = (int*)(erec + E);
    int*    bsum  = start + 2 * N;
    unsigned short* Wt1 = (unsigned short*)(bsum + 256);
    unsigned short* Wt2 = Wt1 + 320 * 64;
    uint2*  rank  = (uint2*)msgB;    // prep-only, dead before msgB first written

    const dim3 blk(256);
    const int tb   = (N + 31) / 32;
    const int gb   = (N + 63) / 64;
    const int e256 = (E + 255) / 256;
    const int n2k  = (2 * N + 1023) / 1024;   // <=128 (scan3 prefix cap)
    const int itot = 2 * N + 320 * 96;
    int* dstart = start + N;

    // ---- prep (5 launches) ----
    init_kernel<<<(itot + 255) / 256, blk, 0, stream>>>(start, 2 * N, W1, root1, W2, root2, Wt1, Wt2);
    count_rank_kernel<<<e256, blk, 0, stream>>>(ei, start, rank, N, E);
    scan1_kernel<<<n2k, 1024, 0, stream>>>(start, bsum, 2 * N);
    scan3_kernel<<<n2k, 1024, 0, stream>>>(start, bsum, 2 * N);
    scatter_plain_kernel<<<e256, blk, 0, stream>>>(ei, pseudo, start, rank, erec, N, E);

    // ---- layers (4 launches) ----
    layer_tm0<<<tb, blk, 0, stream>>>(x, Wt1, b1, start, erec, agg1, (uint4*)msgA, N, E);
    layer_gtm<1><<<tb, blk, 0, stream>>>(agg1, skip, Wt1, b1, start, dstart, erec,
                                         (const uint4*)msgA, (uint4*)msgB, agg2, N, E);
    layer_gtm<2><<<tb, blk, 0, stream>>>(agg2, nullptr, Wt2, b2, start, dstart, erec,
                                         (const uint4*)msgB, (uint4*)msgA, out, N, E);
    gather_kernel<<<gb, blk, 0, stream>>>(dstart, (const uint4*)msgA, out, N, E);
}